// Round 2
// baseline (709.464 us; speedup 1.0000x reference)
//
#include <hip/hip_runtime.h>
#include <math.h>

// Problem constants (fixed by setup_inputs): N=16384, D=4096, E=64, top_k=2.
constexpr int D_DIM = 4096;
constexpr int E_DIM = 64;
constexpr int BM    = 64;      // rows per tile
constexpr int BK    = 64;      // k-chunk
constexpr int NTHREADS = 256;
constexpr int LDX = BM + 4;    // 68: X tile [m][k] m-major, rows 16B-aligned
constexpr int LDW = E_DIM + 4; // 68: W tile [k][e] k-major
constexpr int LDL = E_DIM + 1; // 65: epilogue logits

__global__ __launch_bounds__(NTHREADS, 4) void topk_gate_kernel(
    const float* __restrict__ x, const float* __restrict__ W,
    const float* __restrict__ b, float* __restrict__ out,
    float* __restrict__ partials, int* __restrict__ counters,
    int ksplit, int N)
{
    __shared__ float smem[BK * LDX + BK * LDW];   // 34816 B; epilogue reuses
    __shared__ int s_last;
    float* Xs = smem;             // [BM][LDX]  Xs[m][k]  (m-major!)
    float* Ws = smem + BM * LDX;  // [BK][LDW]  Ws[k][e]

    const int tid  = threadIdx.x;
    const int tn   = tid & 15;          // expert group: cols tn*4..+3
    const int tm   = tid >> 4;          // row group: rows tm*4..+3
    const int bx   = blockIdx.x;
    const int tile = bx / ksplit;
    const int split= bx % ksplit;
    const int row0 = tile * BM;
    const int dk   = D_DIM / ksplit;
    const int koff = split * dk;
    const int ktloc= dk / BK;

    // staging coords
    const int sr  = tid >> 4;           // X: row = p*16+sr
    const int sc4 = tid & 15;           // X: k-float4 index
    const int we  = tid & 63;           // W: expert row
    const int wc  = tid >> 6;           // W: k-base group (wc*16)

    float acc[4][4] = {};

    const float* xblk  = x + (size_t)row0 * D_DIM + koff;
    const float* wbase = W + koff;

    float4 xr[4], wr[4];
    auto load_tile = [&](int t) {
        const float* xg = xblk + t * BK;
        const float* wg = wbase + t * BK;
#pragma unroll
        for (int p = 0; p < 4; ++p)
            xr[p] = *(const float4*)(xg + (size_t)(p * 16 + sr) * D_DIM + sc4 * 4);
#pragma unroll
        for (int q = 0; q < 4; ++q)
            wr[q] = *(const float4*)(wg + (size_t)we * D_DIM + wc * 16 + q * 4);
    };
    auto store_tile = [&]() {
#pragma unroll
        for (int p = 0; p < 4; ++p)   // direct b128, conflict-free at BW floor
            *(float4*)&Xs[(p * 16 + sr) * LDX + sc4 * 4] = xr[p];
#pragma unroll
        for (int q = 0; q < 4; ++q) { // transpose W; lanes vary e -> 2-way, free
            const int k = wc * 16 + q * 4;
            Ws[(k + 0) * LDW + we] = wr[q].x;
            Ws[(k + 1) * LDW + we] = wr[q].y;
            Ws[(k + 2) * LDW + we] = wr[q].z;
            Ws[(k + 3) * LDW + we] = wr[q].w;
        }
    };

    load_tile(0);
    store_tile();
    __syncthreads();

    for (int t = 0; t < ktloc; ++t) {
        if (t + 1 < ktloc) load_tile(t + 1);

#pragma unroll 4
        for (int kg = 0; kg < BK / 4; ++kg) {
            float4 wb0 = *(const float4*)&Ws[(kg * 4 + 0) * LDW + tn * 4];
            float4 wb1 = *(const float4*)&Ws[(kg * 4 + 1) * LDW + tn * 4];
            float4 wb2 = *(const float4*)&Ws[(kg * 4 + 2) * LDW + tn * 4];
            float4 wb3 = *(const float4*)&Ws[(kg * 4 + 3) * LDW + tn * 4];
#pragma unroll
            for (int i = 0; i < 4; ++i) {
                const float4 xa = *(const float4*)&Xs[(tm * 4 + i) * LDX + kg * 4];
                acc[i][0] += xa.x * wb0.x; acc[i][1] += xa.x * wb0.y;
                acc[i][2] += xa.x * wb0.z; acc[i][3] += xa.x * wb0.w;
                acc[i][0] += xa.y * wb1.x; acc[i][1] += xa.y * wb1.y;
                acc[i][2] += xa.y * wb1.z; acc[i][3] += xa.y * wb1.w;
                acc[i][0] += xa.z * wb2.x; acc[i][1] += xa.z * wb2.y;
                acc[i][2] += xa.z * wb2.z; acc[i][3] += xa.z * wb2.w;
                acc[i][0] += xa.w * wb3.x; acc[i][1] += xa.w * wb3.y;
                acc[i][2] += xa.w * wb3.z; acc[i][3] += xa.w * wb3.w;
            }
        }
        __syncthreads();
        if (t + 1 < ktloc) store_tile();
        __syncthreads();
    }

    // ---- epilogue ----
    float* Ls  = smem;                 // [BM][LDL] = 4160 floats
    float* aux = smem + BM * LDL;      // i1[64], i2[64], p1[64], p2[64]

    if (ksplit == 1) {
        const float4 bias = ((const float4*)b)[tn];
#pragma unroll
        for (int i = 0; i < 4; ++i) {
            const int m = tm * 4 + i;
            Ls[m * LDL + tn * 4 + 0] = acc[i][0] + bias.x;
            Ls[m * LDL + tn * 4 + 1] = acc[i][1] + bias.y;
            Ls[m * LDL + tn * 4 + 2] = acc[i][2] + bias.z;
            Ls[m * LDL + tn * 4 + 3] = acc[i][3] + bias.w;
        }
        __syncthreads();
    } else {
        float* my = partials + (size_t)bx * (BM * E_DIM);
#pragma unroll
        for (int i = 0; i < 4; ++i)
            *(float4*)(my + (tm * 4 + i) * E_DIM + tn * 4) =
                make_float4(acc[i][0], acc[i][1], acc[i][2], acc[i][3]);
        __threadfence();   // release: partial visible device-wide
        if (tid == 0) {
            const int old = atomicAdd(&counters[tile], 1);
            s_last = (old == ksplit - 1);
        }
        __syncthreads();
        if (!s_last) return;           // block-uniform exit
        __threadfence();   // acquire: invalidate caches before reading siblings
        const float* base = partials + (size_t)tile * ksplit * (BM * E_DIM);
#pragma unroll
        for (int p = 0; p < 4; ++p) {
            const int f4 = p * 256 + tid;          // 0..1023 float4 of [64][64]
            const int r  = f4 >> 4;
            const int c4 = f4 & 15;
            float4 s = *(const float4*)(base + (size_t)f4 * 4);
            for (int sp = 1; sp < ksplit; ++sp) {
                const float4 t4 = *(const float4*)(base + (size_t)sp * (BM * E_DIM) + (size_t)f4 * 4);
                s.x += t4.x; s.y += t4.y; s.z += t4.z; s.w += t4.w;
            }
            const float4 bb = ((const float4*)b)[c4];
            Ls[r * LDL + c4 * 4 + 0] = s.x + bb.x;
            Ls[r * LDL + c4 * 4 + 1] = s.y + bb.y;
            Ls[r * LDL + c4 * 4 + 2] = s.z + bb.z;
            Ls[r * LDL + c4 * 4 + 3] = s.w + bb.w;
        }
        __syncthreads();
    }

    if (tid < BM) {
        const float* lr = &Ls[tid * LDL];
        float v1 = -INFINITY, v2 = -INFINITY;
        int i1 = 0, i2 = 0;
        for (int e = 0; e < E_DIM; ++e) {   // strict '>' = lax.top_k tie-break
            const float v = lr[e];
            if (v > v1)      { v2 = v1; i2 = i1; v1 = v; i1 = e; }
            else if (v > v2) { v2 = v;  i2 = e; }
        }
        const float ex = expf(v2 - v1);
        const float dn = 1.0f + ex;
        aux[tid]       = (float)i1;
        aux[64 + tid]  = (float)i2;
        aux[128 + tid] = 1.0f / dn;
        aux[192 + tid] = ex / dn;
        const size_t basei = (size_t)N * E_DIM + (size_t)(row0 + tid) * 2;
        out[basei]     = (float)i1;
        out[basei + 1] = (float)i2;
    }
    __syncthreads();

#pragma unroll
    for (int p = 0; p < 4; ++p) {
        const int f4 = p * 256 + tid;
        const int r  = f4 >> 4;
        const int c4 = f4 & 15;
        const int i1 = (int)aux[r];
        const int i2 = (int)aux[64 + r];
        const float p1 = aux[128 + r];
        const float p2 = aux[192 + r];
        const int e = c4 * 4;
        float4 g;
        g.x = (e + 0 == i1) ? p1 : (e + 0 == i2) ? p2 : 0.0f;
        g.y = (e + 1 == i1) ? p1 : (e + 1 == i2) ? p2 : 0.0f;
        g.z = (e + 2 == i1) ? p1 : (e + 2 == i2) ? p2 : 0.0f;
        g.w = (e + 3 == i1) ? p1 : (e + 3 == i2) ? p2 : 0.0f;
        *(float4*)(out + (size_t)(row0 + r) * E_DIM + e) = g;
    }
}

extern "C" void kernel_launch(void* const* d_in, const int* in_sizes, int n_in,
                              void* d_out, int out_size, void* d_ws, size_t ws_size,
                              hipStream_t stream) {
    const float* x = (const float*)d_in[0];
    const float* W = (const float*)d_in[1];
    const float* b = (const float*)d_in[2];
    float* out = (float*)d_out;
    const int N = in_sizes[0] / D_DIM;        // 16384
    const int ntiles = N / BM;                // 256

    const size_t partial_bytes_per_block = (size_t)BM * E_DIM * sizeof(float); // 16 KB
    int ksplit = 1;
    if (ws_size >= (size_t)ntiles * 4 * partial_bytes_per_block + ntiles * sizeof(int))
        ksplit = 4;
    else if (ws_size >= (size_t)ntiles * 2 * partial_bytes_per_block + ntiles * sizeof(int))
        ksplit = 2;

    float* partials = (float*)d_ws;
    int* counters = (int*)((char*)d_ws + (size_t)ntiles * ksplit * partial_bytes_per_block);
    if (ksplit > 1)
        hipMemsetAsync(counters, 0, ntiles * sizeof(int), stream);

    dim3 grid(ntiles * ksplit), block(NTHREADS);
    hipLaunchKernelGGL(topk_gate_kernel, grid, block, 0, stream,
                       x, W, b, out, partials, counters, ksplit, N);
}

// Round 3
// 464.494 us; speedup vs baseline: 1.5274x; 1.5274x over previous
//
#include <hip/hip_runtime.h>
#include <math.h>

// Problem constants (fixed by setup_inputs): N=16384, D=4096, E=64, top_k=2.
constexpr int D_DIM = 4096;
constexpr int E_DIM = 64;
constexpr int BM    = 64;      // rows per tile
constexpr int BK    = 64;      // k-chunk
constexpr int NTHREADS = 256;
constexpr int LDX = BM + 4;    // 68: X tile [m][k] m-major, rows 16B-aligned
constexpr int LDW = E_DIM + 4; // 68: W tile [k][e] k-major
constexpr int LDL = E_DIM + 1; // 65: epilogue logits

// ---------------- kernel 1: split-K GEMM -> fp32 partials ----------------
__global__ __launch_bounds__(NTHREADS, 4) void gemm_partial_kernel(
    const float* __restrict__ x, const float* __restrict__ W,
    float* __restrict__ partials, int ksplit)
{
    __shared__ float smem[BM * LDX + BK * LDW];   // 34816 B -> 4 blocks/CU
    float* Xs = smem;             // [BM][LDX]  Xs[m][k]  (m-major)
    float* Ws = smem + BM * LDX;  // [BK][LDW]  Ws[k][e]

    const int tid  = threadIdx.x;
    const int tn   = tid & 15;          // expert group: cols tn*4..+3
    const int tm   = tid >> 4;          // row group: rows tm*4..+3
    const int bx   = blockIdx.x;
    const int tile = bx / ksplit;
    const int split= bx % ksplit;
    const int row0 = tile * BM;
    const int dk   = D_DIM / ksplit;
    const int koff = split * dk;
    const int ktloc= dk / BK;

    const int sr  = tid >> 4;           // X: row = p*16+sr
    const int sc4 = tid & 15;           // X: k-float4 index
    const int we  = tid & 63;           // W: expert row
    const int wc  = tid >> 6;           // W: k-base group (wc*16)

    float acc[4][4] = {};

    const float* xblk  = x + (size_t)row0 * D_DIM + koff;
    const float* wbase = W + koff;

    float4 xr[4], wr[4];
    auto load_tile = [&](int t) {
#pragma unroll
        for (int p = 0; p < 4; ++p)
            xr[p] = *(const float4*)(xblk + t * BK + (size_t)(p * 16 + sr) * D_DIM + sc4 * 4);
#pragma unroll
        for (int q = 0; q < 4; ++q)
            wr[q] = *(const float4*)(wbase + t * BK + (size_t)we * D_DIM + wc * 16 + q * 4);
    };
    auto store_tile = [&]() {
#pragma unroll
        for (int p = 0; p < 4; ++p)   // direct b128 store, conflict-free
            *(float4*)&Xs[(p * 16 + sr) * LDX + sc4 * 4] = xr[p];
#pragma unroll
        for (int q = 0; q < 4; ++q) { // transpose W; lanes vary e -> 2-way, free
            const int k = wc * 16 + q * 4;
            Ws[(k + 0) * LDW + we] = wr[q].x;
            Ws[(k + 1) * LDW + we] = wr[q].y;
            Ws[(k + 2) * LDW + we] = wr[q].z;
            Ws[(k + 3) * LDW + we] = wr[q].w;
        }
    };

    load_tile(0);
    store_tile();
    __syncthreads();

    for (int t = 0; t < ktloc; ++t) {
        if (t + 1 < ktloc) load_tile(t + 1);

#pragma unroll 4
        for (int kg = 0; kg < BK / 4; ++kg) {
            float4 wb0 = *(const float4*)&Ws[(kg * 4 + 0) * LDW + tn * 4];
            float4 wb1 = *(const float4*)&Ws[(kg * 4 + 1) * LDW + tn * 4];
            float4 wb2 = *(const float4*)&Ws[(kg * 4 + 2) * LDW + tn * 4];
            float4 wb3 = *(const float4*)&Ws[(kg * 4 + 3) * LDW + tn * 4];
#pragma unroll
            for (int i = 0; i < 4; ++i) {
                const float4 xa = *(const float4*)&Xs[(tm * 4 + i) * LDX + kg * 4];
                acc[i][0] += xa.x * wb0.x; acc[i][1] += xa.x * wb0.y;
                acc[i][2] += xa.x * wb0.z; acc[i][3] += xa.x * wb0.w;
                acc[i][0] += xa.y * wb1.x; acc[i][1] += xa.y * wb1.y;
                acc[i][2] += xa.y * wb1.z; acc[i][3] += xa.y * wb1.w;
                acc[i][0] += xa.z * wb2.x; acc[i][1] += xa.z * wb2.y;
                acc[i][2] += xa.z * wb2.z; acc[i][3] += xa.z * wb2.w;
                acc[i][0] += xa.w * wb3.x; acc[i][1] += xa.w * wb3.y;
                acc[i][2] += xa.w * wb3.z; acc[i][3] += xa.w * wb3.w;
            }
        }
        __syncthreads();
        if (t + 1 < ktloc) store_tile();
        __syncthreads();
    }

    // plain stores; kernel boundary provides device-wide visibility
    float* my = partials + (size_t)bx * (BM * E_DIM);
#pragma unroll
    for (int i = 0; i < 4; ++i)
        *(float4*)(my + (tm * 4 + i) * E_DIM + tn * 4) =
            make_float4(acc[i][0], acc[i][1], acc[i][2], acc[i][3]);
}

// ------------- kernel 2: reduce partials + bias + top-2 + gates -------------
__global__ __launch_bounds__(NTHREADS) void topk_finish_kernel(
    const float* __restrict__ partials, const float* __restrict__ b,
    float* __restrict__ out, int ksplit, int N)
{
    __shared__ float smem[BM * LDL + 256];
    float* Ls  = smem;                 // [BM][LDL]
    float* aux = smem + BM * LDL;      // i1[64], i2[64], p1[64], p2[64]

    const int tid  = threadIdx.x;
    const int tile = blockIdx.x;
    const int row0 = tile * BM;
    const float* base = partials + (size_t)tile * ksplit * (BM * E_DIM);

#pragma unroll
    for (int p = 0; p < 4; ++p) {
        const int f4 = p * 256 + tid;          // 0..1023 float4 of [64][64]
        const int r  = f4 >> 4;
        const int c4 = f4 & 15;
        float4 s = *(const float4*)(base + (size_t)f4 * 4);
        for (int sp = 1; sp < ksplit; ++sp) {
            const float4 t4 = *(const float4*)(base + (size_t)sp * (BM * E_DIM) + (size_t)f4 * 4);
            s.x += t4.x; s.y += t4.y; s.z += t4.z; s.w += t4.w;
        }
        const float4 bb = ((const float4*)b)[c4];
        Ls[r * LDL + c4 * 4 + 0] = s.x + bb.x;
        Ls[r * LDL + c4 * 4 + 1] = s.y + bb.y;
        Ls[r * LDL + c4 * 4 + 2] = s.z + bb.z;
        Ls[r * LDL + c4 * 4 + 3] = s.w + bb.w;
    }
    __syncthreads();

    if (tid < BM) {
        const float* lr = &Ls[tid * LDL];
        float v1 = -INFINITY, v2 = -INFINITY;
        int i1 = 0, i2 = 0;
        for (int e = 0; e < E_DIM; ++e) {   // strict '>' = lax.top_k tie-break
            const float v = lr[e];
            if (v > v1)      { v2 = v1; i2 = i1; v1 = v; i1 = e; }
            else if (v > v2) { v2 = v;  i2 = e; }
        }
        const float ex = expf(v2 - v1);
        const float dn = 1.0f + ex;
        aux[tid]       = (float)i1;
        aux[64 + tid]  = (float)i2;
        aux[128 + tid] = 1.0f / dn;
        aux[192 + tid] = ex / dn;
        const size_t basei = (size_t)N * E_DIM + (size_t)(row0 + tid) * 2;
        out[basei]     = (float)i1;    // indices written as float values
        out[basei + 1] = (float)i2;
    }
    __syncthreads();

#pragma unroll
    for (int p = 0; p < 4; ++p) {
        const int f4 = p * 256 + tid;
        const int r  = f4 >> 4;
        const int c4 = f4 & 15;
        const int i1 = (int)aux[r];
        const int i2 = (int)aux[64 + r];
        const float p1 = aux[128 + r];
        const float p2 = aux[192 + r];
        const int e = c4 * 4;
        float4 g;
        g.x = (e + 0 == i1) ? p1 : (e + 0 == i2) ? p2 : 0.0f;
        g.y = (e + 1 == i1) ? p1 : (e + 1 == i2) ? p2 : 0.0f;
        g.z = (e + 2 == i1) ? p1 : (e + 2 == i2) ? p2 : 0.0f;
        g.w = (e + 3 == i1) ? p1 : (e + 3 == i2) ? p2 : 0.0f;
        *(float4*)(out + (size_t)(row0 + r) * E_DIM + e) = g;
    }
}

extern "C" void kernel_launch(void* const* d_in, const int* in_sizes, int n_in,
                              void* d_out, int out_size, void* d_ws, size_t ws_size,
                              hipStream_t stream) {
    const float* x = (const float*)d_in[0];
    const float* W = (const float*)d_in[1];
    const float* b = (const float*)d_in[2];
    float* out = (float*)d_out;
    const int N = in_sizes[0] / D_DIM;        // 16384
    const int ntiles = N / BM;                // 256

    const size_t pbytes = (size_t)BM * E_DIM * sizeof(float); // 16 KB per block
    int ksplit = 1;
    if      (ws_size >= (size_t)ntiles * 4 * pbytes) ksplit = 4;
    else if (ws_size >= (size_t)ntiles * 2 * pbytes) ksplit = 2;

    float* partials = (float*)d_ws;

    hipLaunchKernelGGL(gemm_partial_kernel, dim3(ntiles * ksplit), dim3(NTHREADS),
                       0, stream, x, W, partials, ksplit);
    hipLaunchKernelGGL(topk_finish_kernel, dim3(ntiles), dim3(NTHREADS),
                       0, stream, partials, b, out, ksplit, N);
}

// Round 4
// 405.074 us; speedup vs baseline: 1.7514x; 1.1467x over previous
//
#include <hip/hip_runtime.h>
#include <math.h>

typedef _Float16 f16;
typedef _Float16 f16x8 __attribute__((ext_vector_type(8)));
typedef _Float16 f16x4 __attribute__((ext_vector_type(4)));
typedef float    f32x4 __attribute__((ext_vector_type(4)));

// Problem constants: N=16384, D=4096, E=64, top_k=2.
constexpr int D_DIM = 4096;
constexpr int E_DIM = 64;
constexpr int BM    = 64;      // rows per block -> grid 256
constexpr int BK    = 64;      // k-chunk (2 MFMA k-steps of 32)
constexpr int NT    = 256;
constexpr int LDT   = BK + 8;  // 72 f16 per LDS row (144 B) -> 2-way banks only
constexpr int LDL   = E_DIM + 1;

// Exact power-of-2 scaling keeps all hi/lo residuals in f16 normal range
// (immune to MFMA subnormal flush). logits = acc / 2048 exactly.
constexpr float XSCALE  = 8.0f;
constexpr float WSCALE  = 256.0f;
constexpr float UNSCALE = 1.0f / 2048.0f;

// ---- kernel 0: pack W*256 -> f16 hi/lo planes in workspace ----
__global__ __launch_bounds__(NT) void pack_w(const float* __restrict__ W,
                                             f16* __restrict__ whi,
                                             f16* __restrict__ wlo) {
    const int i = (blockIdx.x * NT + threadIdx.x) * 4;
    const float4 w = *(const float4*)(W + i);
    const float v[4] = {w.x * WSCALE, w.y * WSCALE, w.z * WSCALE, w.w * WSCALE};
    f16x4 hv, lv;
#pragma unroll
    for (int j = 0; j < 4; ++j) {
        const f16 h = (f16)v[j];
        hv[j] = h;
        lv[j] = (f16)(v[j] - (float)h);
    }
    *(f16x4*)(whi + i) = hv;
    *(f16x4*)(wlo + i) = lv;
}

// ---- kernel 1: fused split-f16 MFMA GEMM + bias + top-2 + softmax + gates ----
__global__ __launch_bounds__(NT) void gate_kernel(
    const float* __restrict__ x, const f16* __restrict__ whi,
    const f16* __restrict__ wlo, const float* __restrict__ b,
    float* __restrict__ out, int N)
{
    __shared__ alignas(16) f16 sm[4 * BM * LDT];   // 36864 B; epilogue overlays
    f16* Xh = sm;
    f16* Xl = sm + BM * LDT;
    f16* Wh = sm + 2 * BM * LDT;
    f16* Wl = sm + 3 * BM * LDT;

    const int tid  = threadIdx.x;
    const int row0 = blockIdx.x * BM;

    // staging coords: thread covers rows {r8, 32+r8}, k-slot ks (8 f16)
    const int ks = tid & 7;
    const int r8 = tid >> 3;

    // mfma coords: wave wv owns rows r0..r0+15, all 64 cols
    const int lane = tid & 63;
    const int wv   = tid >> 6;
    const int r0   = wv * 16;
    const int m    = lane & 15;
    const int quad = lane >> 4;

    f32x4 acc[4] = {{0,0,0,0},{0,0,0,0},{0,0,0,0},{0,0,0,0}};

    float4 xr[2][2];
    f16x8 whr[2], wlr[2];

    const float* xblk = x + (size_t)row0 * D_DIM;

    auto load_tile = [&](int t) {
        const int k0 = t * BK;
#pragma unroll
        for (int p = 0; p < 2; ++p) {
            const int r = p * 32 + r8;
            const float* xp = xblk + (size_t)r * D_DIM + k0 + ks * 8;
            xr[p][0] = ((const float4*)xp)[0];
            xr[p][1] = ((const float4*)xp)[1];
            const size_t wo = (size_t)r * D_DIM + k0 + ks * 8;
            whr[p] = *(const f16x8*)(whi + wo);
            wlr[p] = *(const f16x8*)(wlo + wo);
        }
    };
    auto store_tile = [&]() {
#pragma unroll
        for (int p = 0; p < 2; ++p) {
            const int r = p * 32 + r8;
            const float v[8] = {xr[p][0].x * XSCALE, xr[p][0].y * XSCALE,
                                xr[p][0].z * XSCALE, xr[p][0].w * XSCALE,
                                xr[p][1].x * XSCALE, xr[p][1].y * XSCALE,
                                xr[p][1].z * XSCALE, xr[p][1].w * XSCALE};
            f16x8 hv, lv;
#pragma unroll
            for (int j = 0; j < 8; ++j) {
                const f16 h = (f16)v[j];
                hv[j] = h;
                lv[j] = (f16)(v[j] - (float)h);
            }
            *(f16x8*)&Xh[r * LDT + ks * 8] = hv;
            *(f16x8*)&Xl[r * LDT + ks * 8] = lv;
            *(f16x8*)&Wh[r * LDT + ks * 8] = whr[p];
            *(f16x8*)&Wl[r * LDT + ks * 8] = wlr[p];
        }
    };

    load_tile(0);
    store_tile();
    __syncthreads();

    constexpr int KT = D_DIM / BK;   // 64
    for (int t = 0; t < KT; ++t) {
        if (t + 1 < KT) load_tile(t + 1);

#pragma unroll
        for (int kk = 0; kk < 2; ++kk) {
            const int ko = kk * 32 + quad * 8;
            const f16x8 ah = *(const f16x8*)&Xh[(r0 + m) * LDT + ko];
            const f16x8 al = *(const f16x8*)&Xl[(r0 + m) * LDT + ko];
#pragma unroll
            for (int ct = 0; ct < 4; ++ct) {
                const f16x8 bh = *(const f16x8*)&Wh[(ct * 16 + m) * LDT + ko];
                const f16x8 bl = *(const f16x8*)&Wl[(ct * 16 + m) * LDT + ko];
                acc[ct] = __builtin_amdgcn_mfma_f32_16x16x32_f16(ah, bh, acc[ct], 0, 0, 0);
                acc[ct] = __builtin_amdgcn_mfma_f32_16x16x32_f16(ah, bl, acc[ct], 0, 0, 0);
                acc[ct] = __builtin_amdgcn_mfma_f32_16x16x32_f16(al, bh, acc[ct], 0, 0, 0);
            }
        }
        __syncthreads();
        if (t + 1 < KT) store_tile();
        __syncthreads();
    }

    // ---- epilogue: C-layout (col=lane&15, row=quad*4+reg) -> LDS logits ----
    float* Ls  = (float*)sm;          // [BM][LDL] = 4160 floats
    float* aux = Ls + BM * LDL;       // i1[64], i2[64], p1[64], p2[64]

#pragma unroll
    for (int ct = 0; ct < 4; ++ct) {
        const int col = ct * 16 + m;
        const float bb = b[col];
#pragma unroll
        for (int reg = 0; reg < 4; ++reg) {
            const int row = r0 + quad * 4 + reg;
            Ls[row * LDL + col] = acc[ct][reg] * UNSCALE + bb;
        }
    }
    __syncthreads();

    if (tid < BM) {
        const float* lr = &Ls[tid * LDL];
        float v1 = -INFINITY, v2 = -INFINITY;
        int i1 = 0, i2 = 0;
        for (int e = 0; e < E_DIM; ++e) {   // strict '>' = lax.top_k tie-break
            const float v = lr[e];
            if (v > v1)      { v2 = v1; i2 = i1; v1 = v; i1 = e; }
            else if (v > v2) { v2 = v;  i2 = e; }
        }
        const float ex = expf(v2 - v1);
        const float dn = 1.0f + ex;
        aux[tid]       = (float)i1;
        aux[64 + tid]  = (float)i2;
        aux[128 + tid] = 1.0f / dn;
        aux[192 + tid] = ex / dn;
        const size_t basei = (size_t)N * E_DIM + (size_t)(row0 + tid) * 2;
        out[basei]     = (float)i1;   // indices as float values (fp32 out buffer)
        out[basei + 1] = (float)i2;
    }
    __syncthreads();

#pragma unroll
    for (int p = 0; p < 4; ++p) {
        const int f4 = p * 256 + tid;
        const int r  = f4 >> 4;
        const int c4 = f4 & 15;
        const int i1 = (int)aux[r];
        const int i2 = (int)aux[64 + r];
        const float p1 = aux[128 + r];
        const float p2 = aux[192 + r];
        const int e = c4 * 4;
        float4 g;
        g.x = (e + 0 == i1) ? p1 : (e + 0 == i2) ? p2 : 0.0f;
        g.y = (e + 1 == i1) ? p1 : (e + 1 == i2) ? p2 : 0.0f;
        g.z = (e + 2 == i1) ? p1 : (e + 2 == i2) ? p2 : 0.0f;
        g.w = (e + 3 == i1) ? p1 : (e + 3 == i2) ? p2 : 0.0f;
        *(float4*)(out + (size_t)(row0 + r) * E_DIM + e) = g;
    }
}

extern "C" void kernel_launch(void* const* d_in, const int* in_sizes, int n_in,
                              void* d_out, int out_size, void* d_ws, size_t ws_size,
                              hipStream_t stream) {
    const float* x = (const float*)d_in[0];
    const float* W = (const float*)d_in[1];
    const float* b = (const float*)d_in[2];
    float* out = (float*)d_out;
    const int N = in_sizes[0] / D_DIM;        // 16384

    f16* whi = (f16*)d_ws;                     // 64*4096 f16 = 512 KB
    f16* wlo = whi + (size_t)E_DIM * D_DIM;    // +512 KB

    hipLaunchKernelGGL(pack_w, dim3((E_DIM * D_DIM) / (NT * 4)), dim3(NT),
                       0, stream, W, whi, wlo);
    hipLaunchKernelGGL(gate_kernel, dim3(N / BM), dim3(NT),
                       0, stream, x, whi, wlo, b, out, N);
}

// Round 5
// 390.524 us; speedup vs baseline: 1.8167x; 1.0373x over previous
//
#include <hip/hip_runtime.h>
#include <math.h>

typedef _Float16 f16;
typedef _Float16 f16x8 __attribute__((ext_vector_type(8)));
typedef _Float16 f16x4 __attribute__((ext_vector_type(4)));
typedef float    f32x4 __attribute__((ext_vector_type(4)));

// Problem constants: N=16384, D=4096, E=64, top_k=2.
constexpr int D_DIM = 4096;
constexpr int E_DIM = 64;
constexpr int BM    = 64;
constexpr int BK    = 64;      // 2 MFMA k-steps of 32
constexpr int NT    = 256;
constexpr int LDT   = BK + 8;  // 72 f16/row -> 2-way banks only (free)
constexpr int LDL   = E_DIM + 1;

// Exact power-of-2 scaling keeps hi/lo residuals in f16 normal range.
constexpr float XSCALE  = 8.0f;
constexpr float WSCALE  = 256.0f;
constexpr float UNSCALE = 1.0f / 2048.0f;

// ---- kernel 0: pack W*256 -> f16 hi/lo planes in workspace ----
__global__ __launch_bounds__(NT) void pack_w(const float* __restrict__ W,
                                             f16* __restrict__ whi,
                                             f16* __restrict__ wlo) {
    const int i = (blockIdx.x * NT + threadIdx.x) * 4;
    const float4 w = *(const float4*)(W + i);
    const float v[4] = {w.x * WSCALE, w.y * WSCALE, w.z * WSCALE, w.w * WSCALE};
    f16x4 hv, lv;
#pragma unroll
    for (int j = 0; j < 4; ++j) {
        const f16 h = (f16)v[j];
        hv[j] = h;
        lv[j] = (f16)(v[j] - (float)h);
    }
    *(f16x4*)(whi + i) = hv;
    *(f16x4*)(wlo + i) = lv;
}

// ---- kernel 1: split-K MFMA partials; A-fragments straight from global ----
__global__ __launch_bounds__(NT, 4) void gemm_partial(
    const float* __restrict__ x, const f16* __restrict__ whi,
    const f16* __restrict__ wlo, float* __restrict__ partials, int ksplit)
{
    __shared__ alignas(16) f16 Wh[E_DIM * LDT];   // 9216 B
    __shared__ alignas(16) f16 Wl[E_DIM * LDT];   // 9216 B -> 18.4 KB total

    const int tid   = threadIdx.x;
    const int bx    = blockIdx.x;
    const int tile  = bx / ksplit;
    const int split = bx % ksplit;
    const int row0  = tile * BM;
    const int dk    = D_DIM / ksplit;
    const int koff  = split * dk;
    const int KT    = dk / BK;

    // W staging coords: 4 lanes cover one expert row's 32B pair-slot
    const int ks2 = tid & 3;            // k 16-f16 slot pair
    const int we  = tid >> 2;           // expert row 0..63

    // mfma coords
    const int lane = tid & 63;
    const int wv   = tid >> 6;
    const int r0   = wv * 16;
    const int m    = lane & 15;
    const int quad = lane >> 4;

    f32x4 acc[4] = {{0,0,0,0},{0,0,0,0},{0,0,0,0},{0,0,0,0}};

    f16x8 whr[2], wlr[2];
    auto loadW = [&](int t) {
        const size_t o = (size_t)we * D_DIM + koff + t * BK + ks2 * 16;
        whr[0] = *(const f16x8*)(whi + o);
        whr[1] = *(const f16x8*)(whi + o + 8);
        wlr[0] = *(const f16x8*)(wlo + o);
        wlr[1] = *(const f16x8*)(wlo + o + 8);
    };
    auto storeW = [&]() {
        *(f16x8*)&Wh[we * LDT + ks2 * 16]     = whr[0];
        *(f16x8*)&Wh[we * LDT + ks2 * 16 + 8] = whr[1];
        *(f16x8*)&Wl[we * LDT + ks2 * 16]     = wlr[0];
        *(f16x8*)&Wl[we * LDT + ks2 * 16 + 8] = wlr[1];
    };

    // A: lane owns x row (row0+r0+m), k-slice quad*8..+7 of each 32-k step
    const float* xrow = x + (size_t)(row0 + r0 + m) * D_DIM + koff + quad * 8;

    float4 xc[2][2], xn[2][2];
    auto loadX = [&](float4 d[2][2], int t) {
#pragma unroll
        for (int kk = 0; kk < 2; ++kk) {
            const float* p = xrow + t * BK + kk * 32;
            d[kk][0] = ((const float4*)p)[0];
            d[kk][1] = ((const float4*)p)[1];
        }
    };

    loadW(0);
    loadX(xc, 0);
    storeW();
    __syncthreads();

    for (int t = 0; t < KT; ++t) {
        if (t + 1 < KT) { loadW(t + 1); loadX(xn, t + 1); }

#pragma unroll
        for (int kk = 0; kk < 2; ++kk) {
            const float v[8] = {xc[kk][0].x * XSCALE, xc[kk][0].y * XSCALE,
                                xc[kk][0].z * XSCALE, xc[kk][0].w * XSCALE,
                                xc[kk][1].x * XSCALE, xc[kk][1].y * XSCALE,
                                xc[kk][1].z * XSCALE, xc[kk][1].w * XSCALE};
            f16x8 ah, al;
#pragma unroll
            for (int j = 0; j < 8; ++j) {
                const f16 h = (f16)v[j];
                ah[j] = h;
                al[j] = (f16)(v[j] - (float)h);
            }
            const int ko = kk * 32 + quad * 8;
#pragma unroll
            for (int ct = 0; ct < 4; ++ct) {
                const f16x8 bh = *(const f16x8*)&Wh[(ct * 16 + m) * LDT + ko];
                const f16x8 bl = *(const f16x8*)&Wl[(ct * 16 + m) * LDT + ko];
                acc[ct] = __builtin_amdgcn_mfma_f32_16x16x32_f16(ah, bh, acc[ct], 0, 0, 0);
                acc[ct] = __builtin_amdgcn_mfma_f32_16x16x32_f16(al, bh, acc[ct], 0, 0, 0);
                acc[ct] = __builtin_amdgcn_mfma_f32_16x16x32_f16(ah, bl, acc[ct], 0, 0, 0);
            }
        }
        __syncthreads();
        if (t + 1 < KT) {
            storeW();
#pragma unroll
            for (int kk = 0; kk < 2; ++kk) { xc[kk][0] = xn[kk][0]; xc[kk][1] = xn[kk][1]; }
        }
        __syncthreads();
    }

    // fp32 partials (C-layout: col=lane&15, row=quad*4+reg), unscaled here
    float* my = partials + (size_t)bx * (BM * E_DIM);
#pragma unroll
    for (int ct = 0; ct < 4; ++ct)
#pragma unroll
        for (int reg = 0; reg < 4; ++reg)
            my[(r0 + quad * 4 + reg) * E_DIM + ct * 16 + m] = acc[ct][reg] * UNSCALE;
}

// ---- kernel 2: reduce partials + bias + top-2 + softmax + gates ----
__global__ __launch_bounds__(NT) void topk_finish_kernel(
    const float* __restrict__ partials, const float* __restrict__ b,
    float* __restrict__ out, int ksplit, int N)
{
    __shared__ float smem[BM * LDL + 256];
    float* Ls  = smem;
    float* aux = smem + BM * LDL;

    const int tid  = threadIdx.x;
    const int tile = blockIdx.x;
    const int row0 = tile * BM;
    const float* base = partials + (size_t)tile * ksplit * (BM * E_DIM);

#pragma unroll
    for (int p = 0; p < 4; ++p) {
        const int f4 = p * 256 + tid;
        const int r  = f4 >> 4;
        const int c4 = f4 & 15;
        float4 s = *(const float4*)(base + (size_t)f4 * 4);
        for (int sp = 1; sp < ksplit; ++sp) {
            const float4 t4 = *(const float4*)(base + (size_t)sp * (BM * E_DIM) + (size_t)f4 * 4);
            s.x += t4.x; s.y += t4.y; s.z += t4.z; s.w += t4.w;
        }
        const float4 bb = ((const float4*)b)[c4];
        Ls[r * LDL + c4 * 4 + 0] = s.x + bb.x;
        Ls[r * LDL + c4 * 4 + 1] = s.y + bb.y;
        Ls[r * LDL + c4 * 4 + 2] = s.z + bb.z;
        Ls[r * LDL + c4 * 4 + 3] = s.w + bb.w;
    }
    __syncthreads();

    if (tid < BM) {
        const float* lr = &Ls[tid * LDL];
        float v1 = -INFINITY, v2 = -INFINITY;
        int i1 = 0, i2 = 0;
        for (int e = 0; e < E_DIM; ++e) {   // strict '>' = lax.top_k tie-break
            const float v = lr[e];
            if (v > v1)      { v2 = v1; i2 = i1; v1 = v; i1 = e; }
            else if (v > v2) { v2 = v;  i2 = e; }
        }
        const float ex = expf(v2 - v1);
        const float dn = 1.0f + ex;
        aux[tid]       = (float)i1;
        aux[64 + tid]  = (float)i2;
        aux[128 + tid] = 1.0f / dn;
        aux[192 + tid] = ex / dn;
        const size_t basei = (size_t)N * E_DIM + (size_t)(row0 + tid) * 2;
        out[basei]     = (float)i1;   // indices as float values (fp32 out buffer)
        out[basei + 1] = (float)i2;
    }
    __syncthreads();

#pragma unroll
    for (int p = 0; p < 4; ++p) {
        const int f4 = p * 256 + tid;
        const int r  = f4 >> 4;
        const int c4 = f4 & 15;
        const int i1 = (int)aux[r];
        const int i2 = (int)aux[64 + r];
        const float p1 = aux[128 + r];
        const float p2 = aux[192 + r];
        const int e = c4 * 4;
        float4 g;
        g.x = (e + 0 == i1) ? p1 : (e + 0 == i2) ? p2 : 0.0f;
        g.y = (e + 1 == i1) ? p1 : (e + 1 == i2) ? p2 : 0.0f;
        g.z = (e + 2 == i1) ? p1 : (e + 2 == i2) ? p2 : 0.0f;
        g.w = (e + 3 == i1) ? p1 : (e + 3 == i2) ? p2 : 0.0f;
        *(float4*)(out + (size_t)(row0 + r) * E_DIM + e) = g;
    }
}

extern "C" void kernel_launch(void* const* d_in, const int* in_sizes, int n_in,
                              void* d_out, int out_size, void* d_ws, size_t ws_size,
                              hipStream_t stream) {
    const float* x = (const float*)d_in[0];
    const float* W = (const float*)d_in[1];
    const float* b = (const float*)d_in[2];
    float* out = (float*)d_out;
    const int N = in_sizes[0] / D_DIM;        // 16384
    const int ntiles = N / BM;                // 256

    f16* whi = (f16*)d_ws;                         // 512 KB
    f16* wlo = whi + (size_t)E_DIM * D_DIM;        // 512 KB
    float* partials = (float*)(wlo + (size_t)E_DIM * D_DIM);

    const size_t wplanes = 2 * (size_t)E_DIM * D_DIM * sizeof(f16);
    const size_t pbytes  = (size_t)BM * E_DIM * sizeof(float);   // 16 KB/block
    int ksplit = 1;
    if      (ws_size >= wplanes + (size_t)ntiles * 4 * pbytes) ksplit = 4;
    else if (ws_size >= wplanes + (size_t)ntiles * 2 * pbytes) ksplit = 2;

    hipLaunchKernelGGL(pack_w, dim3((E_DIM * D_DIM) / (NT * 4)), dim3(NT),
                       0, stream, W, whi, wlo);
    hipLaunchKernelGGL(gemm_partial, dim3(ntiles * ksplit), dim3(NT),
                       0, stream, x, whi, wlo, partials, ksplit);
    hipLaunchKernelGGL(topk_finish_kernel, dim3(ntiles), dim3(NT),
                       0, stream, partials, b, out, ksplit, N);
}